// Round 9
// baseline (288.417 us; speedup 1.0000x reference)
//
#include <hip/hip_runtime.h>
#include <math.h>

// ---------------------------------------------------------------------------
// HADCommNetwork forward — async-staged MFMA, composite weights, fat-tile flash.
// B=64, N=512, OBS=128, H=256, M=128, ACT=16, T=32768.
// Identity: msg has no activation and only feeds K,V =>
//   K = enc@(Wm·Wk)+(bm·Wk+bk), V = enc@(Wm·Wv)+(bm·Wv+bv)  (msg eliminated).
// flash4b: q-tile 64, 512 threads (8 waves = 4 row-groups x 2 key-halves),
// single-pass exact softmax; K/V staging amortized 2x vs q-tile 32.
// 5 launches: prep_all | enc(+imp) | qkv | flash4b | x+heads
// ---------------------------------------------------------------------------

typedef __attribute__((ext_vector_type(8))) short short8;
typedef __attribute__((ext_vector_type(4))) float f32x4;

#define RSQRT_D 0.08838834764831843f  // 1/sqrt(128)
#define MFMA __builtin_amdgcn_mfma_f32_16x16x32_bf16

__device__ __forceinline__ unsigned short f2bf(float f) {
  union { float f; unsigned u; } v; v.f = f;
  return (unsigned short)((v.u + 0x7FFFu + ((v.u >> 16) & 1u)) >> 16);
}
__device__ __forceinline__ float bf2f(unsigned short h) {
  union { unsigned u; float f; } v; v.u = ((unsigned)h) << 16;
  return v.f;
}
__device__ __forceinline__ unsigned pack2(float a, float b) {
  return (unsigned)f2bf(a) | ((unsigned)f2bf(b) << 16);
}
__device__ __forceinline__ short8 ld8(const unsigned short* p) {
  return *(const short8*)p;
}
__device__ __forceinline__ void gl16(const unsigned short* g,
                                     unsigned short* l) {
  __builtin_amdgcn_global_load_lds(
      (const __attribute__((address_space(1))) unsigned int*)(const void*)g,
      (__attribute__((address_space(3))) unsigned int*)(void*)l, 16, 0, 0);
}

// ---------------- prep: weights + composites + obs + output init ----------------
__global__ __launch_bounds__(256) void prep_all(
    const float* __restrict__ obs, const float* __restrict__ We,
    const float* __restrict__ Wq, const float* __restrict__ Wk,
    const float* __restrict__ Wv, const float* __restrict__ Wp,
    const float* __restrict__ Wc, const float* __restrict__ Wn,
    const float* __restrict__ Wb, const float* __restrict__ bc,
    const float* __restrict__ bn, const float* __restrict__ bb,
    const float* __restrict__ Wa, const float* __restrict__ Wcr,
    const float* __restrict__ ba, const float* __restrict__ bcr,
    const float* __restrict__ bq, const float* __restrict__ bk,
    const float* __restrict__ bv, unsigned short* __restrict__ WeT,
    unsigned short* __restrict__ Wqkv, unsigned short* __restrict__ WpT,
    unsigned short* __restrict__ WaCrT, float* __restrict__ bqkv,
    unsigned short* __restrict__ obs_bf, unsigned short* __restrict__ As,
    unsigned short* __restrict__ Bs, float* __restrict__ logits,
    float* __restrict__ value, float* __restrict__ imp_raw) {
  const int bid = blockIdx.x, tid = threadIdx.x;
  if (bid < 673) {
    int idx = bid * 256 + tid;
    if (idx < 32768) {                 // WeT[n 256][k 128]
      int n = idx >> 7, k = idx & 127;
      WeT[idx] = f2bf(We[k * 256 + n]);
    } else if (idx < 65536) {          // Wqkv rows 0..127: WqT[n 128][k 256]
      int i = idx - 32768;
      int n = i >> 8, k = i & 255;
      Wqkv[i] = f2bf(Wq[k * 128 + n]);
    } else if (idx < 163840) {         // WpT[n 256][k 384]
      int i = idx - 65536;
      int n = i / 384, k = i - n * 384;
      WpT[i] = f2bf(Wp[k * 256 + n]);
    } else if (idx < 172032) {         // WaCrT[32][256]
      int i = idx - 163840;
      int n = i >> 8, k = i & 255;
      float v = (n < 16) ? Wa[k * 16 + n] : (n == 16) ? Wcr[k] : 0.f;
      WaCrT[i] = f2bf(v);
    } else if (idx < 172160) {
      int i = idx - 172032;
      bqkv[i] = bq[i];
    }
  } else if (bid < 2721) {
    // obs prep: 16 tokens/block (4 per wave)
    const int wave = tid >> 6, lane = tid & 63;
    const int t0 = (bid - 673) * 16 + wave * 4;
#pragma unroll
    for (int it = 0; it < 4; ++it) {
      int t = t0 + it;
      const float* row = obs + (size_t)t * 128;
      float2 o = *(const float2*)(row + lane * 2);
      float s2 = o.x * o.x + o.y * o.y;
#pragma unroll
      for (int off = 1; off < 64; off <<= 1) s2 += __shfl_xor(s2, off);
      float inv = 1.f / (sqrtf(s2) + 1e-8f);
      ((unsigned*)obs_bf)[(size_t)t * 64 + lane] = pack2(o.x, o.y);
      ((unsigned*)As)[(size_t)t * 128 + 64 + lane] =
          pack2(o.x * 0.5f * inv, o.y * 0.5f * inv);
      ((unsigned*)Bs)[(size_t)t * 128 + 64 + lane] =
          pack2(o.x * inv, o.y * inv);
    }
  } else if (bid < 4897) {
    int i = (bid - 2721) * 256 + tid;  // 0..557055
    if (i < 524288) logits[i] = ba[i & 15];
    else value[i - 524288] = bcr[0];
  } else if (bid < 5025) {
    imp_raw[(bid - 4897) * 256 + tid] = 0.f;
  } else if (bid < 5057) {
    // composite weights Wqkv rows 128..383: C[i][h] = sum_m W(k|v)[m][i]*Wm[h][m]
    int idx = (bid - 5025) * 256 + tid;  // 0..8191
    int i = idx >> 5;
    int h0 = (idx & 31) * 8;
    const float* Wsrc = (i < 128) ? Wk : Wv;
    const int ic = (i < 128) ? i : (i - 128);
    float acc[8];
#pragma unroll
    for (int e = 0; e < 8; ++e) acc[e] = 0.f;
    for (int m = 0; m < 128; ++m) {
      float w = Wsrc[m * 128 + ic];
#pragma unroll
      for (int e = 0; e < 8; ++e) {
        int h = h0 + e;
        float wm = (m < 32) ? Wc[h * 32 + m]
                 : (m < 96) ? Wn[h * 64 + (m - 32)]
                            : Wb[h * 32 + (m - 96)];
        acc[e] = fmaf(wm, w, acc[e]);
      }
    }
#pragma unroll
    for (int e = 0; e < 8; ++e)
      Wqkv[(size_t)(128 + i) * 256 + h0 + e] = f2bf(acc[e]);
  } else {
    // composite bias: bqkv[128+i] = sum_m bm[m]*W(k|v)[m][i] + (bk|bv)
    int i = tid;
    float acc = (i < 128) ? bk[i] : bv[i - 128];
    const float* Wsrc = (i < 128) ? Wk : Wv;
    const int ic = (i < 128) ? i : (i - 128);
    for (int m = 0; m < 128; ++m) {
      float bmv = (m < 32) ? bc[m] : (m < 96) ? bn[m - 32] : bb[m - 96];
      acc = fmaf(bmv, Wsrc[m * 128 + ic], acc);
    }
    bqkv[128 + i] = acc;
  }
}

// ---------------- enc = relu(obs @ We + be), BK=128 single phase, +imp ----------------
__global__ __launch_bounds__(256, 2) void enc_gemm(
    const unsigned short* __restrict__ obs_bf,
    const unsigned short* __restrict__ WeT, const float* __restrict__ be,
    const float* __restrict__ Wi, unsigned short* __restrict__ enc,
    float* __restrict__ imp_raw) {
  __shared__ unsigned short Asr[16384];
  __shared__ unsigned short Bsr[16384];
  const int tid = threadIdx.x, lane = tid & 63, wave = tid >> 6;
  const int quad = lane >> 4, l16 = lane & 15;
  const int wm = wave & 1, wn = wave >> 1;
  const int bm0 = blockIdx.y * 128, bn0 = blockIdx.x * 128;

#pragma unroll
  for (int it = 0; it < 8; ++it) {
    int c = it * 256 + tid;
    int row = c >> 4, ch = c & 15;
    gl16(obs_bf + (size_t)(bm0 + row) * 128 + ((ch ^ (row & 15)) << 3),
         Asr + it * 2048 + wave * 512);
    gl16(WeT + (size_t)(bn0 + row) * 128 + ((ch ^ (row & 15)) << 3),
         Bsr + it * 2048 + wave * 512);
  }
  __syncthreads();

  f32x4 acc[4][4];
#pragma unroll
  for (int i = 0; i < 4; ++i)
#pragma unroll
    for (int j = 0; j < 4; ++j) acc[i][j] = (f32x4){0.f, 0.f, 0.f, 0.f};
#pragma unroll
  for (int ks = 0; ks < 4; ++ks) {
    short8 af[4], bf[4];
#pragma unroll
    for (int mi = 0; mi < 4; ++mi) {
      int row = wm * 64 + mi * 16 + l16;
      af[mi] = *(const short8*)&Asr[row * 128 + (((ks * 4 + quad) ^ (row & 15)) << 3)];
    }
#pragma unroll
    for (int ni = 0; ni < 4; ++ni) {
      int row = wn * 64 + ni * 16 + l16;
      bf[ni] = *(const short8*)&Bsr[row * 128 + (((ks * 4 + quad) ^ (row & 15)) << 3)];
    }
#pragma unroll
    for (int mi = 0; mi < 4; ++mi)
#pragma unroll
      for (int ni = 0; ni < 4; ++ni)
        acc[mi][ni] = MFMA(af[mi], bf[ni], acc[mi][ni], 0, 0, 0);
  }

#pragma unroll
  for (int mi = 0; mi < 4; ++mi) {
    const int rowb = bm0 + wm * 64 + mi * 16 + quad * 4;
    float ip[4] = {0.f, 0.f, 0.f, 0.f};
#pragma unroll
    for (int ni = 0; ni < 4; ++ni) {
      const int col = bn0 + wn * 64 + ni * 16 + l16;
      const float bvv = be[col], wv = Wi[col];
#pragma unroll
      for (int r = 0; r < 4; ++r) {
        float v = fmaxf(acc[mi][ni][r] + bvv, 0.f);
        enc[(size_t)(rowb + r) * 256 + col] = f2bf(v);
        ip[r] += v * wv;
      }
    }
#pragma unroll
    for (int r = 0; r < 4; ++r) {
#pragma unroll
      for (int off = 1; off < 16; off <<= 1) ip[r] += __shfl_xor(ip[r], off);
    }
    if (l16 == 0) {
#pragma unroll
      for (int r = 0; r < 4; ++r) atomicAdd(&imp_raw[rowb + r], ip[r]);
    }
  }
}

// ---------------- qkv GEMM: enc @ Wqkv (N=384, K=256), tri-epilogue ----------------
__global__ __launch_bounds__(256, 2) void qkv_gemm(
    const unsigned short* __restrict__ enc, const unsigned short* __restrict__ Wqkv,
    const float* __restrict__ bqkv, const float* __restrict__ imp_raw,
    const float* __restrict__ bi, unsigned short* __restrict__ As,
    unsigned short* __restrict__ Bs, unsigned short* __restrict__ vT) {
  __shared__ unsigned short Asr[8192];
  __shared__ unsigned short Bsr[8192];
  const int tid = threadIdx.x, lane = tid & 63, wave = tid >> 6;
  const int quad = lane >> 4, l16 = lane & 15;
  const int wm = wave & 1, wn = wave >> 1;
  const int bx = blockIdx.x;
  const int bm0 = blockIdx.y * 128, bn0 = bx * 128;
  const int srow = tid >> 3, slc = tid & 7;

  f32x4 acc[4][4];
#pragma unroll
  for (int i = 0; i < 4; ++i)
#pragma unroll
    for (int j = 0; j < 4; ++j) acc[i][j] = (f32x4){0.f, 0.f, 0.f, 0.f};

  for (int kt = 0; kt < 256; kt += 64) {
#pragma unroll
    for (int i = 0; i < 4; ++i) {
      int row = i * 32 + srow;
      gl16(enc + (size_t)(bm0 + row) * 256 + kt + ((slc ^ (row & 7)) << 3),
           Asr + i * 2048 + wave * 512);
      gl16(Wqkv + (size_t)(bn0 + row) * 256 + kt + ((slc ^ (row & 7)) << 3),
           Bsr + i * 2048 + wave * 512);
    }
    __syncthreads();
#pragma unroll
    for (int ks = 0; ks < 2; ++ks) {
      short8 af[4], bf[4];
#pragma unroll
      for (int mi = 0; mi < 4; ++mi) {
        int row = wm * 64 + mi * 16 + l16;
        af[mi] = *(const short8*)&Asr[row * 64 + (((ks * 4 + quad) ^ (row & 7)) << 3)];
      }
#pragma unroll
      for (int ni = 0; ni < 4; ++ni) {
        int row = wn * 64 + ni * 16 + l16;
        bf[ni] = *(const short8*)&Bsr[row * 64 + (((ks * 4 + quad) ^ (row & 7)) << 3)];
      }
#pragma unroll
      for (int mi = 0; mi < 4; ++mi)
#pragma unroll
        for (int ni = 0; ni < 4; ++ni)
          acc[mi][ni] = MFMA(af[mi], bf[ni], acc[mi][ni], 0, 0, 0);
    }
    __syncthreads();
  }

  const float bi0 = bi[0];
#pragma unroll
  for (int mi = 0; mi < 4; ++mi) {
    const int rowb = bm0 + wm * 64 + mi * 16 + quad * 4;
    float sg[4];
    if (bx < 2) {
      const float mult = (bx == 0) ? RSQRT_D : 1.0f;
#pragma unroll
      for (int r = 0; r < 4; ++r)
        sg[r] = mult / (1.f + __expf(-(imp_raw[rowb + r] + bi0)));
    }
#pragma unroll
    for (int ni = 0; ni < 4; ++ni) {
      const int col = wn * 64 + ni * 16 + l16;
      const float bvv = bqkv[bx * 128 + col];
      if (bx == 0) {
#pragma unroll
        for (int r = 0; r < 4; ++r)
          As[(size_t)(rowb + r) * 256 + col] = f2bf((acc[mi][ni][r] + bvv) * sg[r]);
      } else if (bx == 1) {
#pragma unroll
        for (int r = 0; r < 4; ++r)
          Bs[(size_t)(rowb + r) * 256 + col] = f2bf((acc[mi][ni][r] + bvv) * sg[r]);
      } else {
        uint2 o;
        o.x = pack2(acc[mi][ni][0] + bvv, acc[mi][ni][1] + bvv);
        o.y = pack2(acc[mi][ni][2] + bvv, acc[mi][ni][3] + bvv);
        *(uint2*)(vT + ((size_t)(rowb >> 9) * 128 + col) * 512 + (rowb & 511)) = o;
      }
    }
  }
}

// ---------------- flash4b: q-tile 64, 512 threads, single-pass softmax ----------------
// 512 blocks: b = id&63 (XCD-local), qt = id>>6 (8 q-tiles of 64).
// 8 waves: wm = wave&3 (16-row group), wn = wave>>2 (64-key half of staged 128).
__global__ __launch_bounds__(512, 4) void flash4b(
    const unsigned short* __restrict__ As, const unsigned short* __restrict__ Bs,
    const unsigned short* __restrict__ vT, unsigned short* __restrict__ agg) {
  __shared__ unsigned short Ub[16384];  // 32 KB
  __shared__ unsigned short Pp[8192];   // 16 KB (64 q x 128 keys)
  __shared__ float redm[2][64];
  __shared__ float reds[2][64];
  const int tid = threadIdx.x, lane = tid & 63, wave = tid >> 6;
  const int quad = lane >> 4, l16 = lane & 15;
  const int wm = wave & 3, wn = wave >> 2;
  const int b = blockIdx.x & 63;
  const int qt = blockIdx.x >> 6;
  const size_t tok0 = (size_t)b * 512 + qt * 64;
  const int srow = tid >> 4, slc = tid & 15;  // 32 rows per stage iter

  short8 af[8];
#pragma unroll
  for (int kc = 0; kc < 8; ++kc)
    af[kc] = ld8(As + (tok0 + wm * 16 + l16) * 256 + kc * 32 + quad * 8);

  f32x4 s[4][4];
#pragma unroll
  for (int kt = 0; kt < 4; ++kt)
#pragma unroll
    for (int nt = 0; nt < 4; ++nt) s[kt][nt] = (f32x4){0.f, 0.f, 0.f, 0.f};

  // ---- QK^T over all 512 keys (4 tiles x 2 k-halves) ----
#pragma unroll
  for (int kt = 0; kt < 4; ++kt) {
#pragma unroll
    for (int kh = 0; kh < 2; ++kh) {
      __syncthreads();
#pragma unroll
      for (int i = 0; i < 4; ++i) {
        int row = i * 32 + srow;
        gl16(Bs + ((size_t)b * 512 + kt * 128 + row) * 256 + kh * 128 +
                 ((slc ^ (row & 15)) << 3),
             Ub + i * 4096 + wave * 512);
      }
      __syncthreads();
#pragma unroll
      for (int kk = 0; kk < 4; ++kk) {
        short8 bfr[4];
#pragma unroll
        for (int nt = 0; nt < 4; ++nt) {
          int rr = wn * 64 + nt * 16 + l16;
          bfr[nt] = *(const short8*)&Ub[rr * 128 + (((kk * 4 + quad) ^ (rr & 15)) << 3)];
        }
#pragma unroll
        for (int nt = 0; nt < 4; ++nt)
          s[kt][nt] = MFMA(af[kh * 4 + kk], bfr[nt], s[kt][nt], 0, 0, 0);
      }
    }
  }

  // ---- exact softmax (rows = wm*16 + quad*4 + r) ----
  const int rbase = wm * 16 + quad * 4;
  float mt[4];
#pragma unroll
  for (int r = 0; r < 4; ++r) {
    float mv = -1e30f;
#pragma unroll
    for (int kt = 0; kt < 4; ++kt)
#pragma unroll
      for (int nt = 0; nt < 4; ++nt) mv = fmaxf(mv, s[kt][nt][r]);
#pragma unroll
    for (int off = 1; off < 16; off <<= 1) mv = fmaxf(mv, __shfl_xor(mv, off));
    mt[r] = mv;
  }
  if (l16 == 0) {
#pragma unroll
    for (int r = 0; r < 4; ++r) redm[wn][rbase + r] = mt[r];
  }
  __syncthreads();
  float lsum[4];
#pragma unroll
  for (int r = 0; r < 4; ++r) {
    float mfull = fmaxf(mt[r], redm[1 ^ wn][rbase + r]);
    float sum = 0.f;
#pragma unroll
    for (int kt = 0; kt < 4; ++kt)
#pragma unroll
      for (int nt = 0; nt < 4; ++nt) {
        float p = __expf(s[kt][nt][r] - mfull);
        s[kt][nt][r] = p;
        sum += p;
      }
#pragma unroll
    for (int off = 1; off < 16; off <<= 1) sum += __shfl_xor(sum, off);
    lsum[r] = sum;
  }
  if (l16 == 0) {
#pragma unroll
    for (int r = 0; r < 4; ++r) reds[wn][rbase + r] = lsum[r];
  }
  __syncthreads();
  float linv[4];
#pragma unroll
  for (int r = 0; r < 4; ++r)
    linv[r] = 1.0f / (lsum[r] + reds[1 ^ wn][rbase + r]);

  // ---- PV over 4 key chunks ----
  f32x4 oacc[4];
#pragma unroll
  for (int nt = 0; nt < 4; ++nt) oacc[nt] = (f32x4){0.f, 0.f, 0.f, 0.f};
#pragma unroll
  for (int vt = 0; vt < 4; ++vt) {
    __syncthreads();
    // P chunk (64 q x 128 keys) -> LDS, A-operand layout
#pragma unroll
    for (int nt = 0; nt < 4; ++nt) {
      const int col = wn * 64 + nt * 16 + l16;
#pragma unroll
      for (int r = 0; r < 4; ++r) {
        const int row = rbase + r;
        Pp[row * 128 + (((col >> 3) ^ (row & 15)) << 3) + (col & 7)] =
            f2bf(s[vt][nt][r]);
      }
    }
    // V chunk: vT[d 0..128)[keys vt*128..+128)
#pragma unroll
    for (int i = 0; i < 4; ++i) {
      int row = i * 32 + srow;
      gl16(vT + ((size_t)b * 128 + row) * 512 + vt * 128 +
               ((slc ^ (row & 15)) << 3),
           Ub + i * 4096 + wave * 512);
    }
    __syncthreads();
#pragma unroll
    for (int kk = 0; kk < 4; ++kk) {
      const int prow = wm * 16 + l16;
      short8 pa = *(const short8*)&Pp[prow * 128 + (((kk * 4 + quad) ^ (prow & 15)) << 3)];
#pragma unroll
      for (int nt = 0; nt < 4; ++nt) {
        int rr = wn * 64 + nt * 16 + l16;
        short8 vb = *(const short8*)&Ub[rr * 128 + (((kk * 4 + quad) ^ (rr & 15)) << 3)];
        oacc[nt] = MFMA(pa, vb, oacc[nt], 0, 0, 0);
      }
    }
  }
#pragma unroll
  for (int nt = 0; nt < 4; ++nt) {
    const int col = wn * 64 + nt * 16 + l16;
#pragma unroll
    for (int r = 0; r < 4; ++r)
      agg[(tok0 + rbase + r) * 128 + col] = f2bf(oacc[nt][r] * linv[r]);
  }
}

// ---------------- x-GEMM (128x128) + fused heads ----------------
__global__ __launch_bounds__(256, 2) void xh_gemm(
    const unsigned short* __restrict__ enc, const unsigned short* __restrict__ agg,
    const unsigned short* __restrict__ WpT, const float* __restrict__ bp,
    const unsigned short* __restrict__ WaCrT, float* __restrict__ logits,
    float* __restrict__ value) {
  __shared__ unsigned short sm[16384];
  unsigned short* Asr = sm;
  unsigned short* Bsr = sm + 8192;
  const int tid = threadIdx.x, lane = tid & 63, wave = tid >> 6;
  const int quad = lane >> 4, l16 = lane & 15;
  const int wm = wave & 1, wn = wave >> 1;
  const int bm = blockIdx.y * 128, bn = blockIdx.x * 128;
  const int srow = tid >> 3, slc = tid & 7;

  f32x4 acc[4][4];
#pragma unroll
  for (int i = 0; i < 4; ++i)
#pragma unroll
    for (int j = 0; j < 4; ++j) acc[i][j] = (f32x4){0.f, 0.f, 0.f, 0.f};

  for (int kt = 0; kt < 384; kt += 64) {
    const unsigned short* Ap;
    int lda, kloc;
    if (kt < 256) { Ap = enc; lda = 256; kloc = kt; }
    else          { Ap = agg; lda = 128; kloc = kt - 256; }
#pragma unroll
    for (int i = 0; i < 4; ++i) {
      int row = i * 32 + srow;
      gl16(Ap + (size_t)(bm + row) * lda + kloc + ((slc ^ (row & 7)) << 3),
           Asr + i * 2048 + wave * 512);
      gl16(WpT + (size_t)(bn + row) * 384 + kt + ((slc ^ (row & 7)) << 3),
           Bsr + i * 2048 + wave * 512);
    }
    __syncthreads();
#pragma unroll
    for (int ks = 0; ks < 2; ++ks) {
      short8 af[4], bf[4];
#pragma unroll
      for (int mi = 0; mi < 4; ++mi) {
        int row = wm * 64 + mi * 16 + l16;
        af[mi] = *(const short8*)&Asr[row * 64 + (((ks * 4 + quad) ^ (row & 7)) << 3)];
      }
#pragma unroll
      for (int ni = 0; ni < 4; ++ni) {
        int row = wn * 64 + ni * 16 + l16;
        bf[ni] = *(const short8*)&Bsr[row * 64 + (((ks * 4 + quad) ^ (row & 7)) << 3)];
      }
#pragma unroll
      for (int mi = 0; mi < 4; ++mi)
#pragma unroll
        for (int ni = 0; ni < 4; ++ni)
          acc[mi][ni] = MFMA(af[mi], bf[ni], acc[mi][ni], 0, 0, 0);
    }
    __syncthreads();
  }

#pragma unroll
  for (int mi = 0; mi < 4; ++mi) {
    const int row = wm * 64 + mi * 16 + quad * 4;
#pragma unroll
    for (int ni = 0; ni < 4; ++ni) {
      const int colc = wn * 64 + ni * 16 + l16;
      const float bv = bp[bn + colc];
#pragma unroll
      for (int r = 0; r < 4; ++r) {
        float v = fmaxf(acc[mi][ni][r] + bv, 0.f);
        sm[(row + r) * 128 + (((colc >> 3) ^ ((row + r) & 15)) << 3) + (colc & 7)] =
            f2bf(v);
      }
    }
  }
  __syncthreads();

  f32x4 h[2][2];
#pragma unroll
  for (int i = 0; i < 2; ++i)
#pragma unroll
    for (int j = 0; j < 2; ++j) h[i][j] = (f32x4){0.f, 0.f, 0.f, 0.f};
#pragma unroll
  for (int kc = 0; kc < 4; ++kc) {
    short8 xa[2], wb[2];
#pragma unroll
    for (int hm = 0; hm < 2; ++hm) {
      int row = wave * 32 + hm * 16 + l16;
      xa[hm] = *(const short8*)&sm[row * 128 + (((kc * 4 + quad) ^ (row & 15)) << 3)];
    }
#pragma unroll
    for (int hn = 0; hn < 2; ++hn)
      wb[hn] = ld8(WaCrT + (size_t)(hn * 16 + l16) * 256 + bn + kc * 32 + quad * 8);
#pragma unroll
    for (int hm = 0; hm < 2; ++hm)
#pragma unroll
      for (int hn = 0; hn < 2; ++hn)
        h[hm][hn] = MFMA(xa[hm], wb[hn], h[hm][hn], 0, 0, 0);
  }
#pragma unroll
  for (int hm = 0; hm < 2; ++hm) {
#pragma unroll
    for (int hn = 0; hn < 2; ++hn) {
      const int n = hn * 16 + l16;
#pragma unroll
      for (int r = 0; r < 4; ++r) {
        const int grow = bm + wave * 32 + hm * 16 + quad * 4 + r;
        if (n < 16)
          atomicAdd(&logits[(size_t)grow * 16 + n], h[hm][hn][r]);
        else if (n == 16)
          atomicAdd(&value[grow], h[hm][hn][r]);
      }
    }
  }
}

// ---------------------------------------------------------------------------
extern "C" void kernel_launch(void* const* d_in, const int* in_sizes, int n_in,
                              void* d_out, int out_size, void* d_ws,
                              size_t ws_size, hipStream_t stream) {
  const float* obs = (const float*)d_in[0];
  const float* We = (const float*)d_in[2];
  const float* be = (const float*)d_in[3];
  const float* Wc = (const float*)d_in[4];
  const float* bc = (const float*)d_in[5];
  const float* Wn = (const float*)d_in[6];
  const float* bn = (const float*)d_in[7];
  const float* Wb = (const float*)d_in[8];
  const float* bb = (const float*)d_in[9];
  const float* Wi = (const float*)d_in[10];
  const float* bi = (const float*)d_in[11];
  const float* Wq = (const float*)d_in[12];
  const float* bq = (const float*)d_in[13];
  const float* Wk = (const float*)d_in[14];
  const float* bk = (const float*)d_in[15];
  const float* Wv = (const float*)d_in[16];
  const float* bv = (const float*)d_in[17];
  const float* Wp = (const float*)d_in[18];
  const float* bp = (const float*)d_in[19];
  const float* Wa = (const float*)d_in[20];
  const float* ba = (const float*)d_in[21];
  const float* Wcr = (const float*)d_in[22];
  const float* bcr = (const float*)d_in[23];

  char* base = (char*)d_ws;
  unsigned short* enc_bf = (unsigned short*)(base);              // 16.78 MB
  unsigned short* As     = (unsigned short*)(base + 16777216);   // 16.78 MB
  unsigned short* Bs     = (unsigned short*)(base + 33554432);   // 16.78 MB
  unsigned short* obsagg = (unsigned short*)(base + 50331648);   // 8.39 MB (obs_bf -> agg)
  unsigned short* vT     = (unsigned short*)(base + 58720256);   // 8.39 MB
  float* imp_raw         = (float*)(base + 67108864);            // 128 KB
  unsigned short* WeT    = (unsigned short*)(base + 67239936);   // 64 KB
  unsigned short* Wqkv   = (unsigned short*)(base + 67305472);   // 192 KB
  unsigned short* WpT    = (unsigned short*)(base + 67502080);   // 192 KB
  unsigned short* WaCrT  = (unsigned short*)(base + 67698688);   // 16 KB
  float* bqkv            = (float*)(base + 67715072);            // 1.5 KB

  float* logits = (float*)d_out;
  float* value = (float*)d_out + 524288;

  prep_all<<<5058, 256, 0, stream>>>(obs, We, Wq, Wk, Wv, Wp, Wc, Wn, Wb, bc,
                                     bn, bb, Wa, Wcr, ba, bcr, bq, bk, bv,
                                     WeT, Wqkv, WpT, WaCrT, bqkv, obsagg, As,
                                     Bs, logits, value, imp_raw);

  enc_gemm<<<dim3(2, 256), 256, 0, stream>>>(obsagg, WeT, be, Wi, enc_bf,
                                             imp_raw);
  qkv_gemm<<<dim3(3, 256), 256, 0, stream>>>(enc_bf, Wqkv, bqkv, imp_raw, bi,
                                             As, Bs, vT);
  flash4b<<<512, 512, 0, stream>>>(As, Bs, vT, obsagg);
  xh_gemm<<<dim3(2, 256), 256, 0, stream>>>(enc_bf, obsagg, WpT, bp, WaCrT,
                                            logits, value);
}

// Round 10
// 182.165 us; speedup vs baseline: 1.5833x; 1.5833x over previous
//
#include <hip/hip_runtime.h>
#include <math.h>

// ---------------------------------------------------------------------------
// HADCommNetwork forward — async-staged MFMA, composite weights, fat-tile flash.
// B=64, N=512, OBS=128, H=256, M=128, ACT=16, T=32768.
// Identity: msg has no activation and only feeds K,V =>
//   K = enc@(Wm·Wk)+(bm·Wk+bk), V = enc@(Wm·Wv)+(bm·Wv+bv)  (msg eliminated).
// prep_wprod computes the composite via MFMA (r7 form — r9's scalar fold was a
// 124 µs latency-bound straggler). flash4b: q-tile 64, 512 threads.
// 6 launches: prep_all | prep_wprod | enc(+imp) | qkv | flash4b | x+heads
// ---------------------------------------------------------------------------

typedef __attribute__((ext_vector_type(8))) short short8;
typedef __attribute__((ext_vector_type(4))) float f32x4;

#define RSQRT_D 0.08838834764831843f  // 1/sqrt(128)
#define MFMA __builtin_amdgcn_mfma_f32_16x16x32_bf16

__device__ __forceinline__ unsigned short f2bf(float f) {
  union { float f; unsigned u; } v; v.f = f;
  return (unsigned short)((v.u + 0x7FFFu + ((v.u >> 16) & 1u)) >> 16);
}
__device__ __forceinline__ float bf2f(unsigned short h) {
  union { unsigned u; float f; } v; v.u = ((unsigned)h) << 16;
  return v.f;
}
__device__ __forceinline__ unsigned pack2(float a, float b) {
  return (unsigned)f2bf(a) | ((unsigned)f2bf(b) << 16);
}
__device__ __forceinline__ short8 ld8(const unsigned short* p) {
  return *(const short8*)p;
}
__device__ __forceinline__ void gl16(const unsigned short* g,
                                     unsigned short* l) {
  __builtin_amdgcn_global_load_lds(
      (const __attribute__((address_space(1))) unsigned int*)(const void*)g,
      (__attribute__((address_space(3))) unsigned int*)(void*)l, 16, 0, 0);
}

// ---------------- prep: weights + obs + output init (r7 form) ----------------
__global__ __launch_bounds__(256) void prep_all(
    const float* __restrict__ obs, const float* __restrict__ We,
    const float* __restrict__ Wq, const float* __restrict__ Wk,
    const float* __restrict__ Wv, const float* __restrict__ Wp,
    const float* __restrict__ Wc, const float* __restrict__ Wn,
    const float* __restrict__ Wb, const float* __restrict__ bc,
    const float* __restrict__ bn, const float* __restrict__ bb,
    const float* __restrict__ Wa, const float* __restrict__ Wcr,
    const float* __restrict__ ba, const float* __restrict__ bcr,
    const float* __restrict__ bq, unsigned short* __restrict__ WeT,
    unsigned short* __restrict__ Wqkv, unsigned short* __restrict__ Wkv,
    unsigned short* __restrict__ Wm_nt, unsigned short* __restrict__ WpT,
    unsigned short* __restrict__ WaCrT, float* __restrict__ bm,
    float* __restrict__ bqkv, unsigned short* __restrict__ obs_bf,
    unsigned short* __restrict__ As, unsigned short* __restrict__ Bs,
    float* __restrict__ logits, float* __restrict__ value,
    float* __restrict__ imp_raw) {
  const int bid = blockIdx.x, tid = threadIdx.x;
  if (bid < 929) {
    int idx = bid * 256 + tid;
    if (idx < 32768) {                 // WeT[n 256][k 128]
      int n = idx >> 7, k = idx & 127;
      WeT[idx] = f2bf(We[k * 256 + n]);
    } else if (idx < 65536) {          // Wqkv rows 0..127: WqT[n 128][k 256]
      int i = idx - 32768;
      int n = i >> 8, k = i & 255;
      Wqkv[i] = f2bf(Wq[k * 128 + n]);
    } else if (idx < 98304) {          // Wkv[n 256][k 128] = [WkT; WvT]
      int i = idx - 65536;
      int n = i >> 7, k = i & 127;
      Wkv[i] = f2bf(n < 128 ? Wk[k * 128 + n] : Wv[k * 128 + (n - 128)]);
    } else if (idx < 131072) {         // Wm_nt[h 256][m 128] (packed Wm)
      int i = idx - 98304;
      int h = i >> 7, m = i & 127;
      float v = (m < 32)   ? Wc[h * 32 + m]
              : (m < 96)   ? Wn[h * 64 + (m - 32)]
                           : Wb[h * 32 + (m - 96)];
      Wm_nt[i] = f2bf(v);
    } else if (idx < 229376) {         // WpT[n 256][k 384]
      int i = idx - 131072;
      int n = i / 384, k = i - n * 384;
      WpT[i] = f2bf(Wp[k * 256 + n]);
    } else if (idx < 237568) {         // WaCrT[32][256]
      int i = idx - 229376;
      int n = i >> 8, k = i & 255;
      float v = (n < 16) ? Wa[k * 16 + n] : (n == 16) ? Wcr[k] : 0.f;
      WaCrT[i] = f2bf(v);
    } else if (idx < 237696) {
      int i = idx - 237568;
      bm[i] = (i < 32) ? bc[i] : (i < 96) ? bn[i - 32] : bb[i - 96];
    } else if (idx < 237824) {
      int i = idx - 237696;
      bqkv[i] = bq[i];
    }
  } else if (bid < 2977) {
    // obs prep: 16 tokens/block (4 per wave)
    const int wave = tid >> 6, lane = tid & 63;
    const int t0 = (bid - 929) * 16 + wave * 4;
#pragma unroll
    for (int it = 0; it < 4; ++it) {
      int t = t0 + it;
      const float* row = obs + (size_t)t * 128;
      float2 o = *(const float2*)(row + lane * 2);
      float s2 = o.x * o.x + o.y * o.y;
#pragma unroll
      for (int off = 1; off < 64; off <<= 1) s2 += __shfl_xor(s2, off);
      float inv = 1.f / (sqrtf(s2) + 1e-8f);
      ((unsigned*)obs_bf)[(size_t)t * 64 + lane] = pack2(o.x, o.y);
      ((unsigned*)As)[(size_t)t * 128 + 64 + lane] =
          pack2(o.x * 0.5f * inv, o.y * 0.5f * inv);
      ((unsigned*)Bs)[(size_t)t * 128 + 64 + lane] =
          pack2(o.x * inv, o.y * inv);
    }
  } else if (bid < 5153) {
    int i = (bid - 2977) * 256 + tid;
    if (i < 524288) logits[i] = ba[i & 15];
    else value[i - 524288] = bcr[0];
  } else {
    imp_raw[(bid - 5153) * 256 + tid] = 0.f;
  }
}

// ---------------- composite weights via MFMA: Wqkv rows 128..383 + bqkv ----------------
__global__ __launch_bounds__(256) void prep_wprod(
    const unsigned short* __restrict__ Wkv,
    const unsigned short* __restrict__ Wm_nt, const float* __restrict__ bm,
    const float* __restrict__ bk, const float* __restrict__ bv,
    unsigned short* __restrict__ Wqkv, float* __restrict__ bqkv) {
  const int bid = blockIdx.x, tid = threadIdx.x;
  if (bid < 8) {
    const int lane = tid & 63, wave = tid >> 6;
    const int quad = lane >> 4, l16 = lane & 15;
    const int r0 = bid * 32;
    f32x4 acc[2][4];
#pragma unroll
    for (int i = 0; i < 2; ++i)
#pragma unroll
      for (int j = 0; j < 4; ++j) acc[i][j] = (f32x4){0.f, 0.f, 0.f, 0.f};
#pragma unroll
    for (int kc = 0; kc < 4; ++kc) {
      short8 af[2], bf[4];
#pragma unroll
      for (int i = 0; i < 2; ++i)
        af[i] = ld8(Wkv + (size_t)(r0 + i * 16 + l16) * 128 + kc * 32 + quad * 8);
#pragma unroll
      for (int j = 0; j < 4; ++j)
        bf[j] = ld8(Wm_nt + (size_t)(wave * 64 + j * 16 + l16) * 128 + kc * 32 +
                    quad * 8);
#pragma unroll
      for (int i = 0; i < 2; ++i)
#pragma unroll
        for (int j = 0; j < 4; ++j)
          acc[i][j] = MFMA(af[i], bf[j], acc[i][j], 0, 0, 0);
    }
#pragma unroll
    for (int i = 0; i < 2; ++i) {
      const int row = r0 + i * 16 + quad * 4;
#pragma unroll
      for (int j = 0; j < 4; ++j) {
        const int col = wave * 64 + j * 16 + l16;
#pragma unroll
        for (int r = 0; r < 4; ++r)
          Wqkv[(size_t)(128 + row + r) * 256 + col] = f2bf(acc[i][j][r]);
      }
    }
  } else {
    int i = tid;
    float acc = (i < 128) ? bk[i] : bv[i - 128];
    for (int m = 0; m < 128; ++m)
      acc += bm[m] * bf2f(Wkv[(size_t)i * 128 + m]);
    bqkv[128 + i] = acc;
  }
}

// ---------------- enc = relu(obs @ We + be), BK=128 single phase, +imp ----------------
__global__ __launch_bounds__(256, 2) void enc_gemm(
    const unsigned short* __restrict__ obs_bf,
    const unsigned short* __restrict__ WeT, const float* __restrict__ be,
    const float* __restrict__ Wi, unsigned short* __restrict__ enc,
    float* __restrict__ imp_raw) {
  __shared__ unsigned short Asr[16384];
  __shared__ unsigned short Bsr[16384];
  const int tid = threadIdx.x, lane = tid & 63, wave = tid >> 6;
  const int quad = lane >> 4, l16 = lane & 15;
  const int wm = wave & 1, wn = wave >> 1;
  const int bm0 = blockIdx.y * 128, bn0 = blockIdx.x * 128;

#pragma unroll
  for (int it = 0; it < 8; ++it) {
    int c = it * 256 + tid;
    int row = c >> 4, ch = c & 15;
    gl16(obs_bf + (size_t)(bm0 + row) * 128 + ((ch ^ (row & 15)) << 3),
         Asr + it * 2048 + wave * 512);
    gl16(WeT + (size_t)(bn0 + row) * 128 + ((ch ^ (row & 15)) << 3),
         Bsr + it * 2048 + wave * 512);
  }
  __syncthreads();

  f32x4 acc[4][4];
#pragma unroll
  for (int i = 0; i < 4; ++i)
#pragma unroll
    for (int j = 0; j < 4; ++j) acc[i][j] = (f32x4){0.f, 0.f, 0.f, 0.f};
#pragma unroll
  for (int ks = 0; ks < 4; ++ks) {
    short8 af[4], bf[4];
#pragma unroll
    for (int mi = 0; mi < 4; ++mi) {
      int row = wm * 64 + mi * 16 + l16;
      af[mi] = *(const short8*)&Asr[row * 128 + (((ks * 4 + quad) ^ (row & 15)) << 3)];
    }
#pragma unroll
    for (int ni = 0; ni < 4; ++ni) {
      int row = wn * 64 + ni * 16 + l16;
      bf[ni] = *(const short8*)&Bsr[row * 128 + (((ks * 4 + quad) ^ (row & 15)) << 3)];
    }
#pragma unroll
    for (int mi = 0; mi < 4; ++mi)
#pragma unroll
      for (int ni = 0; ni < 4; ++ni)
        acc[mi][ni] = MFMA(af[mi], bf[ni], acc[mi][ni], 0, 0, 0);
  }

#pragma unroll
  for (int mi = 0; mi < 4; ++mi) {
    const int rowb = bm0 + wm * 64 + mi * 16 + quad * 4;
    float ip[4] = {0.f, 0.f, 0.f, 0.f};
#pragma unroll
    for (int ni = 0; ni < 4; ++ni) {
      const int col = bn0 + wn * 64 + ni * 16 + l16;
      const float bvv = be[col], wv = Wi[col];
#pragma unroll
      for (int r = 0; r < 4; ++r) {
        float v = fmaxf(acc[mi][ni][r] + bvv, 0.f);
        enc[(size_t)(rowb + r) * 256 + col] = f2bf(v);
        ip[r] += v * wv;
      }
    }
#pragma unroll
    for (int r = 0; r < 4; ++r) {
#pragma unroll
      for (int off = 1; off < 16; off <<= 1) ip[r] += __shfl_xor(ip[r], off);
    }
    if (l16 == 0) {
#pragma unroll
      for (int r = 0; r < 4; ++r) atomicAdd(&imp_raw[rowb + r], ip[r]);
    }
  }
}

// ---------------- qkv GEMM: enc @ Wqkv (N=384, K=256), tri-epilogue ----------------
__global__ __launch_bounds__(256, 2) void qkv_gemm(
    const unsigned short* __restrict__ enc, const unsigned short* __restrict__ Wqkv,
    const float* __restrict__ bqkv, const float* __restrict__ imp_raw,
    const float* __restrict__ bi, unsigned short* __restrict__ As,
    unsigned short* __restrict__ Bs, unsigned short* __restrict__ vT) {
  __shared__ unsigned short Asr[8192];
  __shared__ unsigned short Bsr[8192];
  const int tid = threadIdx.x, lane = tid & 63, wave = tid >> 6;
  const int quad = lane >> 4, l16 = lane & 15;
  const int wm = wave & 1, wn = wave >> 1;
  const int bx = blockIdx.x;
  const int bm0 = blockIdx.y * 128, bn0 = bx * 128;
  const int srow = tid >> 3, slc = tid & 7;

  f32x4 acc[4][4];
#pragma unroll
  for (int i = 0; i < 4; ++i)
#pragma unroll
    for (int j = 0; j < 4; ++j) acc[i][j] = (f32x4){0.f, 0.f, 0.f, 0.f};

  for (int kt = 0; kt < 256; kt += 64) {
#pragma unroll
    for (int i = 0; i < 4; ++i) {
      int row = i * 32 + srow;
      gl16(enc + (size_t)(bm0 + row) * 256 + kt + ((slc ^ (row & 7)) << 3),
           Asr + i * 2048 + wave * 512);
      gl16(Wqkv + (size_t)(bn0 + row) * 256 + kt + ((slc ^ (row & 7)) << 3),
           Bsr + i * 2048 + wave * 512);
    }
    __syncthreads();
#pragma unroll
    for (int ks = 0; ks < 2; ++ks) {
      short8 af[4], bf[4];
#pragma unroll
      for (int mi = 0; mi < 4; ++mi) {
        int row = wm * 64 + mi * 16 + l16;
        af[mi] = *(const short8*)&Asr[row * 64 + (((ks * 4 + quad) ^ (row & 7)) << 3)];
      }
#pragma unroll
      for (int ni = 0; ni < 4; ++ni) {
        int row = wn * 64 + ni * 16 + l16;
        bf[ni] = *(const short8*)&Bsr[row * 64 + (((ks * 4 + quad) ^ (row & 7)) << 3)];
      }
#pragma unroll
      for (int mi = 0; mi < 4; ++mi)
#pragma unroll
        for (int ni = 0; ni < 4; ++ni)
          acc[mi][ni] = MFMA(af[mi], bf[ni], acc[mi][ni], 0, 0, 0);
    }
    __syncthreads();
  }

  const float bi0 = bi[0];
#pragma unroll
  for (int mi = 0; mi < 4; ++mi) {
    const int rowb = bm0 + wm * 64 + mi * 16 + quad * 4;
    float sg[4];
    if (bx < 2) {
      const float mult = (bx == 0) ? RSQRT_D : 1.0f;
#pragma unroll
      for (int r = 0; r < 4; ++r)
        sg[r] = mult / (1.f + __expf(-(imp_raw[rowb + r] + bi0)));
    }
#pragma unroll
    for (int ni = 0; ni < 4; ++ni) {
      const int col = wn * 64 + ni * 16 + l16;
      const float bvv = bqkv[bx * 128 + col];
      if (bx == 0) {
#pragma unroll
        for (int r = 0; r < 4; ++r)
          As[(size_t)(rowb + r) * 256 + col] = f2bf((acc[mi][ni][r] + bvv) * sg[r]);
      } else if (bx == 1) {
#pragma unroll
        for (int r = 0; r < 4; ++r)
          Bs[(size_t)(rowb + r) * 256 + col] = f2bf((acc[mi][ni][r] + bvv) * sg[r]);
      } else {
        uint2 o;
        o.x = pack2(acc[mi][ni][0] + bvv, acc[mi][ni][1] + bvv);
        o.y = pack2(acc[mi][ni][2] + bvv, acc[mi][ni][3] + bvv);
        *(uint2*)(vT + ((size_t)(rowb >> 9) * 128 + col) * 512 + (rowb & 511)) = o;
      }
    }
  }
}

// ---------------- flash4b: q-tile 64, 512 threads, single-pass softmax ----------------
// 512 blocks: b = id&63 (XCD-local), qt = id>>6 (8 q-tiles of 64).
// 8 waves: wm = wave&3 (16-row group), wn = wave>>2 (64-key half of staged 128).
__global__ __launch_bounds__(512, 4) void flash4b(
    const unsigned short* __restrict__ As, const unsigned short* __restrict__ Bs,
    const unsigned short* __restrict__ vT, unsigned short* __restrict__ agg) {
  __shared__ unsigned short Ub[16384];  // 32 KB
  __shared__ unsigned short Pp[8192];   // 16 KB (64 q x 128 keys)
  __shared__ float redm[2][64];
  __shared__ float reds[2][64];
  const int tid = threadIdx.x, lane = tid & 63, wave = tid >> 6;
  const int quad = lane >> 4, l16 = lane & 15;
  const int wm = wave & 3, wn = wave >> 2;
  const int b = blockIdx.x & 63;
  const int qt = blockIdx.x >> 6;
  const size_t tok0 = (size_t)b * 512 + qt * 64;
  const int srow = tid >> 4, slc = tid & 15;  // 32 rows per stage iter

  short8 af[8];
#pragma unroll
  for (int kc = 0; kc < 8; ++kc)
    af[kc] = ld8(As + (tok0 + wm * 16 + l16) * 256 + kc * 32 + quad * 8);

  f32x4 s[4][4];
#pragma unroll
  for (int kt = 0; kt < 4; ++kt)
#pragma unroll
    for (int nt = 0; nt < 4; ++nt) s[kt][nt] = (f32x4){0.f, 0.f, 0.f, 0.f};

  // ---- QK^T over all 512 keys (4 tiles x 2 k-halves) ----
#pragma unroll
  for (int kt = 0; kt < 4; ++kt) {
#pragma unroll
    for (int kh = 0; kh < 2; ++kh) {
      __syncthreads();
#pragma unroll
      for (int i = 0; i < 4; ++i) {
        int row = i * 32 + srow;
        gl16(Bs + ((size_t)b * 512 + kt * 128 + row) * 256 + kh * 128 +
                 ((slc ^ (row & 15)) << 3),
             Ub + i * 4096 + wave * 512);
      }
      __syncthreads();
#pragma unroll
      for (int kk = 0; kk < 4; ++kk) {
        short8 bfr[4];
#pragma unroll
        for (int nt = 0; nt < 4; ++nt) {
          int rr = wn * 64 + nt * 16 + l16;
          bfr[nt] = *(const short8*)&Ub[rr * 128 + (((kk * 4 + quad) ^ (rr & 15)) << 3)];
        }
#pragma unroll
        for (int nt = 0; nt < 4; ++nt)
          s[kt][nt] = MFMA(af[kh * 4 + kk], bfr[nt], s[kt][nt], 0, 0, 0);
      }
    }
  }

  // ---- exact softmax (rows = wm*16 + quad*4 + r) ----
  const int rbase = wm * 16 + quad * 4;
  float mt[4];
#pragma unroll
  for (int r = 0; r < 4; ++r) {
    float mv = -1e30f;
#pragma unroll
    for (int kt = 0; kt < 4; ++kt)
#pragma unroll
      for (int nt = 0; nt < 4; ++nt) mv = fmaxf(mv, s[kt][nt][r]);
#pragma unroll
    for (int off = 1; off < 16; off <<= 1) mv = fmaxf(mv, __shfl_xor(mv, off));
    mt[r] = mv;
  }
  if (l16 == 0) {
#pragma unroll
    for (int r = 0; r < 4; ++r) redm[wn][rbase + r] = mt[r];
  }
  __syncthreads();
  float lsum[4];
#pragma unroll
  for (int r = 0; r < 4; ++r) {
    float mfull = fmaxf(mt[r], redm[1 ^ wn][rbase + r]);
    float sum = 0.f;
#pragma unroll
    for (int kt = 0; kt < 4; ++kt)
#pragma unroll
      for (int nt = 0; nt < 4; ++nt) {
        float p = __expf(s[kt][nt][r] - mfull);
        s[kt][nt][r] = p;
        sum += p;
      }
#pragma unroll
    for (int off = 1; off < 16; off <<= 1) sum += __shfl_xor(sum, off);
    lsum[r] = sum;
  }
  if (l16 == 0) {
#pragma unroll
    for (int r = 0; r < 4; ++r) reds[wn][rbase + r] = lsum[r];
  }
  __syncthreads();
  float linv[4];
#pragma unroll
  for (int r = 0; r < 4; ++r)
    linv[r] = 1.0f / (lsum[r] + reds[1 ^ wn][rbase + r]);

  // ---- PV over 4 key chunks ----
  f32x4 oacc[4];
#pragma unroll
  for (int nt = 0; nt < 4; ++nt) oacc[nt] = (f32x4){0.f, 0.f, 0.f, 0.f};
#pragma unroll
  for (int vt = 0; vt < 4; ++vt) {
    __syncthreads();
    // P chunk (64 q x 128 keys) -> LDS, A-operand layout
#pragma unroll
    for (int nt = 0; nt < 4; ++nt) {
      const int col = wn * 64 + nt * 16 + l16;
#pragma unroll
      for (int r = 0; r < 4; ++r) {
        const int row = rbase + r;
        Pp[row * 128 + (((col >> 3) ^ (row & 15)) << 3) + (col & 7)] =
            f2bf(s[vt][nt][r]);
      }
    }
    // V chunk: vT[d 0..128)[keys vt*128..+128)
#pragma unroll
    for (int i = 0; i < 4; ++i) {
      int row = i * 32 + srow;
      gl16(vT + ((size_t)b * 128 + row) * 512 + vt * 128 +
               ((slc ^ (row & 15)) << 3),
           Ub + i * 4096 + wave * 512);
    }
    __syncthreads();
#pragma unroll
    for (int kk = 0; kk < 4; ++kk) {
      const int prow = wm * 16 + l16;
      short8 pa = *(const short8*)&Pp[prow * 128 + (((kk * 4 + quad) ^ (prow & 15)) << 3)];
#pragma unroll
      for (int nt = 0; nt < 4; ++nt) {
        int rr = wn * 64 + nt * 16 + l16;
        short8 vb = *(const short8*)&Ub[rr * 128 + (((kk * 4 + quad) ^ (rr & 15)) << 3)];
        oacc[nt] = MFMA(pa, vb, oacc[nt], 0, 0, 0);
      }
    }
  }
#pragma unroll
  for (int nt = 0; nt < 4; ++nt) {
    const int col = wn * 64 + nt * 16 + l16;
#pragma unroll
    for (int r = 0; r < 4; ++r)
      agg[(tok0 + rbase + r) * 128 + col] = f2bf(oacc[nt][r] * linv[r]);
  }
}

// ---------------- x-GEMM (128x128) + fused heads ----------------
__global__ __launch_bounds__(256, 2) void xh_gemm(
    const unsigned short* __restrict__ enc, const unsigned short* __restrict__ agg,
    const unsigned short* __restrict__ WpT, const float* __restrict__ bp,
    const unsigned short* __restrict__ WaCrT, float* __restrict__ logits,
    float* __restrict__ value) {
  __shared__ unsigned short sm[16384];
  unsigned short* Asr = sm;
  unsigned short* Bsr = sm + 8192;
  const int tid = threadIdx.x, lane = tid & 63, wave = tid >> 6;
  const int quad = lane >> 4, l16 = lane & 15;
  const int wm = wave & 1, wn = wave >> 1;
  const int bm = blockIdx.y * 128, bn = blockIdx.x * 128;
  const int srow = tid >> 3, slc = tid & 7;

  f32x4 acc[4][4];
#pragma unroll
  for (int i = 0; i < 4; ++i)
#pragma unroll
    for (int j = 0; j < 4; ++j) acc[i][j] = (f32x4){0.f, 0.f, 0.f, 0.f};

  for (int kt = 0; kt < 384; kt += 64) {
    const unsigned short* Ap;
    int lda, kloc;
    if (kt < 256) { Ap = enc; lda = 256; kloc = kt; }
    else          { Ap = agg; lda = 128; kloc = kt - 256; }
#pragma unroll
    for (int i = 0; i < 4; ++i) {
      int row = i * 32 + srow;
      gl16(Ap + (size_t)(bm + row) * lda + kloc + ((slc ^ (row & 7)) << 3),
           Asr + i * 2048 + wave * 512);
      gl16(WpT + (size_t)(bn + row) * 384 + kt + ((slc ^ (row & 7)) << 3),
           Bsr + i * 2048 + wave * 512);
    }
    __syncthreads();
#pragma unroll
    for (int ks = 0; ks < 2; ++ks) {
      short8 af[4], bf[4];
#pragma unroll
      for (int mi = 0; mi < 4; ++mi) {
        int row = wm * 64 + mi * 16 + l16;
        af[mi] = *(const short8*)&Asr[row * 64 + (((ks * 4 + quad) ^ (row & 7)) << 3)];
      }
#pragma unroll
      for (int ni = 0; ni < 4; ++ni) {
        int row = wn * 64 + ni * 16 + l16;
        bf[ni] = *(const short8*)&Bsr[row * 64 + (((ks * 4 + quad) ^ (row & 7)) << 3)];
      }
#pragma unroll
      for (int mi = 0; mi < 4; ++mi)
#pragma unroll
        for (int ni = 0; ni < 4; ++ni)
          acc[mi][ni] = MFMA(af[mi], bf[ni], acc[mi][ni], 0, 0, 0);
    }
    __syncthreads();
  }

#pragma unroll
  for (int mi = 0; mi < 4; ++mi) {
    const int row = wm * 64 + mi * 16 + quad * 4;
#pragma unroll
    for (int ni = 0; ni < 4; ++ni) {
      const int colc = wn * 64 + ni * 16 + l16;
      const float bv = bp[bn + colc];
#pragma unroll
      for (int r = 0; r < 4; ++r) {
        float v = fmaxf(acc[mi][ni][r] + bv, 0.f);
        sm[(row + r) * 128 + (((colc >> 3) ^ ((row + r) & 15)) << 3) + (colc & 7)] =
            f2bf(v);
      }
    }
  }
  __syncthreads();

  f32x4 h[2][2];
#pragma unroll
  for (int i = 0; i < 2; ++i)
#pragma unroll
    for (int j = 0; j < 2; ++j) h[i][j] = (f32x4){0.f, 0.f, 0.f, 0.f};
#pragma unroll
  for (int kc = 0; kc < 4; ++kc) {
    short8 xa[2], wb[2];
#pragma unroll
    for (int hm = 0; hm < 2; ++hm) {
      int row = wave * 32 + hm * 16 + l16;
      xa[hm] = *(const short8*)&sm[row * 128 + (((kc * 4 + quad) ^ (row & 15)) << 3)];
    }
#pragma unroll
    for (int hn = 0; hn < 2; ++hn)
      wb[hn] = ld8(WaCrT + (size_t)(hn * 16 + l16) * 256 + bn + kc * 32 + quad * 8);
#pragma unroll
    for (int hm = 0; hm < 2; ++hm)
#pragma unroll
      for (int hn = 0; hn < 2; ++hn)
        h[hm][hn] = MFMA(xa[hm], wb[hn], h[hm][hn], 0, 0, 0);
  }
#pragma unroll
  for (int hm = 0; hm < 2; ++hm) {
#pragma unroll
    for (int hn = 0; hn < 2; ++hn) {
      const int n = hn * 16 + l16;
#pragma unroll
      for (int r = 0; r < 4; ++r) {
        const int grow = bm + wave * 32 + hm * 16 + quad * 4 + r;
        if (n < 16)
          atomicAdd(&logits[(size_t)grow * 16 + n], h[hm][hn][r]);
        else if (n == 16)
          atomicAdd(&value[grow], h[hm][hn][r]);
      }
    }
  }
}

// ---------------------------------------------------------------------------
extern "C" void kernel_launch(void* const* d_in, const int* in_sizes, int n_in,
                              void* d_out, int out_size, void* d_ws,
                              size_t ws_size, hipStream_t stream) {
  const float* obs = (const float*)d_in[0];
  const float* We = (const float*)d_in[2];
  const float* be = (const float*)d_in[3];
  const float* Wc = (const float*)d_in[4];
  const float* bc = (const float*)d_in[5];
  const float* Wn = (const float*)d_in[6];
  const float* bn = (const float*)d_in[7];
  const float* Wb = (const float*)d_in[8];
  const float* bb = (const float*)d_in[9];
  const float* Wi = (const float*)d_in[10];
  const float* bi = (const float*)d_in[11];
  const float* Wq = (const float*)d_in[12];
  const float* bq = (const float*)d_in[13];
  const float* Wk = (const float*)d_in[14];
  const float* bk = (const float*)d_in[15];
  const float* Wv = (const float*)d_in[16];
  const float* bv = (const float*)d_in[17];
  const float* Wp = (const float*)d_in[18];
  const float* bp = (const float*)d_in[19];
  const float* Wa = (const float*)d_in[20];
  const float* ba = (const float*)d_in[21];
  const float* Wcr = (const float*)d_in[22];
  const float* bcr = (const float*)d_in[23];

  char* base = (char*)d_ws;
  unsigned short* enc_bf = (unsigned short*)(base);              // 16.78 MB
  unsigned short* As     = (unsigned short*)(base + 16777216);   // 16.78 MB
  unsigned short* Bs     = (unsigned short*)(base + 33554432);   // 16.78 MB
  unsigned short* obsagg = (unsigned short*)(base + 50331648);   // 8.39 MB (obs_bf -> agg)
  unsigned short* vT     = (unsigned short*)(base + 58720256);   // 8.39 MB
  float* imp_raw         = (float*)(base + 67108864);            // 128 KB
  unsigned short* WeT    = (unsigned short*)(base + 67239936);   // 64 KB
  unsigned short* Wqkv   = (unsigned short*)(base + 67305472);   // 192 KB
  unsigned short* Wkv    = (unsigned short*)(base + 67502080);   // 64 KB
  unsigned short* Wm_nt  = (unsigned short*)(base + 67567616);   // 64 KB
  unsigned short* WpT    = (unsigned short*)(base + 67633152);   // 192 KB
  unsigned short* WaCrT  = (unsigned short*)(base + 67829760);   // 16 KB
  float* bmb             = (float*)(base + 67846144);            // 512 B
  float* bqkv            = (float*)(base + 67846656);            // 1.5 KB

  float* logits = (float*)d_out;
  float* value = (float*)d_out + 524288;

  prep_all<<<5281, 256, 0, stream>>>(obs, We, Wq, Wk, Wv, Wp, Wc, Wn, Wb, bc,
                                     bn, bb, Wa, Wcr, ba, bcr, bq, WeT, Wqkv,
                                     Wkv, Wm_nt, WpT, WaCrT, bmb, bqkv, obsagg,
                                     As, Bs, logits, value, imp_raw);
  prep_wprod<<<9, 256, 0, stream>>>(Wkv, Wm_nt, bmb, bk, bv, Wqkv, bqkv);

  enc_gemm<<<dim3(2, 256), 256, 0, stream>>>(obsagg, WeT, be, Wi, enc_bf,
                                             imp_raw);
  qkv_gemm<<<dim3(3, 256), 256, 0, stream>>>(enc_bf, Wqkv, bqkv, imp_raw, bi,
                                             As, Bs, vT);
  flash4b<<<512, 512, 0, stream>>>(As, Bs, vT, obsagg);
  xh_gemm<<<dim3(2, 256), 256, 0, stream>>>(enc_bf, obsagg, WpT, bp, WaCrT,
                                            logits, value);
}